// Round 10
// baseline (293.818 us; speedup 1.0000x reference)
//
#include <hip/hip_runtime.h>
#include <hip/hip_bf16.h>

#define T_STEPS 100
#define D_IN    65536
#define HID     256
#define HTOT    512
#define BETA    0.95f
#define THRESH  1.0f

typedef __bf16 bf16x8 __attribute__((ext_vector_type(8)));
typedef float  f32x16 __attribute__((ext_vector_type(16)));

__device__ __forceinline__ void gload_lds16(const void* g, void* l) {
    __builtin_amdgcn_global_load_lds(
        (const __attribute__((address_space(1))) void*)g,
        (__attribute__((address_space(3))) void*)l, 16, 0, 0);
}

// ---- x pre-pack: fp32 -> bf16 hi/mid blobs, one 16-KB blob per 32-k block.
// Blob layout == gemm1 LDS x-layout: granule G(r,slot) = r*4 + (slot^((r>>1)&3)),
// hi at G*16 bytes, mid at 8 KB + G*16. Rows 100..127 zero-padded.
__global__ __launch_bounds__(512) void k_xpack(
    const float* __restrict__ x, __bf16* __restrict__ xp)
{
    const int idx  = blockIdx.x * 512 + threadIdx.x;
    const int slot = idx & 3;
    const int r    = (idx >> 2) & 127;
    const int gk   = idx >> 9;

    float f[8] = {0.f, 0.f, 0.f, 0.f, 0.f, 0.f, 0.f, 0.f};
    if (r < T_STEPS) {
        const float* src = x + (size_t)r * D_IN + gk * 32 + slot * 8;
        float4 v0 = *(const float4*)src;
        float4 v1 = *(const float4*)(src + 4);
        f[0] = v0.x; f[1] = v0.y; f[2] = v0.z; f[3] = v0.w;
        f[4] = v1.x; f[5] = v1.y; f[6] = v1.z; f[7] = v1.w;
    }
    bf16x8 hi, mi;
#pragma unroll
    for (int e = 0; e < 8; e++) {
        __bf16 h = (__bf16)f[e];
        hi[e] = h; mi[e] = (__bf16)(f[e] - (float)h);
    }
    const int G = r * 4 + (slot ^ ((r >> 1) & 3));
    __bf16* blob = xp + (size_t)gk * 8192;
    *(bf16x8*)(blob + G * 8)        = hi;
    *(bf16x8*)(blob + 4096 + G * 8) = mi;
}

// ---- GEMM1: small-block / 4-resident-blocks-per-CU pipeline.
// Block = 32h x 128t, step = 32k. Per-step buffer 20 KB: [0,16K) x blob copy
// (hi|mid), [16K,20K) W fp32 (64 granules x ... = 32 rows x 8 swizzled 16B).
// Double-buffered = 40 KB exactly -> 4 blocks/CU. 5 gload_lds/thread/step,
// vmcnt(5) steady. 3-product bf16 hi/mid MFMA, k ascending (order == R8).
// grid: (16 h-tiles of 32, NS k-splits), block 256 = 4 waves (wave = 32t x 32h).
__global__ __launch_bounds__(256, 4) void k_gemm1(
    const float* __restrict__ aW1,   // [256][65536]
    const float* __restrict__ cW1,   // [256][65536]
    const __bf16* __restrict__ xp,   // packed x blobs
    float* __restrict__ P,           // [NS][100][512]
    int nsteps)                      // 32-k steps per split
{
    const int ht   = blockIdx.x;     // 0..15 (global h-rows [ht*32, ht*32+32))
    const int s    = blockIdx.y;     // k-split
    const int tid  = threadIdx.x;
    const int lane = tid & 63;
    const int l31  = lane & 31;
    const int h5   = lane >> 5;      // k-half within k16
    const int wv   = tid >> 6;       // 0..3
    const int wt   = wv * 32;        // wave t-offset

    __shared__ __align__(16) char smem[2][20480];   // 40 KB

    const float* Wbase = (ht < 8) ? (aW1 + (size_t)ht * 32 * D_IN)
                                  : (cW1 + (size_t)(ht - 8) * 32 * D_IN);

    // staging: ops 0..3 = x blob (linear copy), op 4 = W granule
    const int wrow = tid >> 3, wg = tid & 7;       // 32 rows x 8 granules
    const float* wsrc = Wbase + (size_t)wrow * D_IN + (wg ^ (wrow & 7)) * 4;
    const int gk0 = s * nsteps;

    f32x16 acc;
#pragma unroll
    for (int i = 0; i < 16; i++) acc[i] = 0.f;

#define STAGE(i) do {                                                         \
    char* b_ = smem[(i) & 1];                                                 \
    const __bf16* xb_ = xp + (size_t)(gk0 + (i)) * 8192;                      \
    const int kc_ = (gk0 + (i)) * 32;                                         \
    gload_lds16(xb_ + (tid +   0) * 8, b_ + (tid +   0) * 16);                \
    gload_lds16(xb_ + (tid + 256) * 8, b_ + (tid + 256) * 16);                \
    gload_lds16(xb_ + (tid + 512) * 8, b_ + (tid + 512) * 16);                \
    gload_lds16(xb_ + (tid + 768) * 8, b_ + (tid + 768) * 16);                \
    gload_lds16(wsrc + kc_, b_ + 16384 + tid * 16);                           \
} while (0)

#define COMPUTE(i) do {                                                       \
    const char* b_ = smem[(i) & 1];                                           \
    _Pragma("unroll")                                                         \
    for (int s16 = 0; s16 < 2; s16++) {                                       \
        /* W B-fragment from LDS (swizzled) + convert */                      \
        const int hr_ = l31;                                                  \
        const int gb_ = s16 * 4 + h5 * 2;                                     \
        const char* wrow_ = b_ + 16384 + hr_ * 128;                           \
        float4 wa = *(const float4*)(wrow_ + ((gb_ ^ (hr_ & 7)) * 16));       \
        float4 wb = *(const float4*)(wrow_ + (((gb_ + 1) ^ (hr_ & 7)) * 16)); \
        float fb[8] = {wa.x, wa.y, wa.z, wa.w, wb.x, wb.y, wb.z, wb.w};       \
        bf16x8 bh, bm;                                                        \
        _Pragma("unroll")                                                     \
        for (int e = 0; e < 8; e++) {                                         \
            __bf16 h = (__bf16)fb[e];                                         \
            bh[e] = h; bm[e] = (__bf16)(fb[e] - (float)h);                    \
        }                                                                     \
        /* x A-fragment from LDS blob copy */                                 \
        const int slot_ = s16 * 2 + h5;                                       \
        const int r0_   = wt + l31;                                           \
        const int G0_   = r0_ * 4 + (slot_ ^ ((r0_ >> 1) & 3));               \
        bf16x8 a0h = *(const bf16x8*)(b_ + G0_ * 16);                         \
        bf16x8 a0m = *(const bf16x8*)(b_ + 8192 + G0_ * 16);                  \
        acc = __builtin_amdgcn_mfma_f32_32x32x16_bf16(a0m, bh, acc, 0, 0, 0); \
        acc = __builtin_amdgcn_mfma_f32_32x32x16_bf16(a0h, bm, acc, 0, 0, 0); \
        acc = __builtin_amdgcn_mfma_f32_32x32x16_bf16(a0h, bh, acc, 0, 0, 0); \
    }                                                                         \
} while (0)

    STAGE(0);
    STAGE(1);
    for (int i = 0; i < nsteps; i++) {
        if (i + 1 < nsteps) asm volatile("s_waitcnt vmcnt(5)" ::: "memory");
        else                asm volatile("s_waitcnt vmcnt(0)" ::: "memory");
        __builtin_amdgcn_s_barrier();              // buf[i&1] staged for all
        __builtin_amdgcn_sched_barrier(0);
        COMPUTE(i);
        __builtin_amdgcn_s_barrier();              // all waves done with buf
        __builtin_amdgcn_sched_barrier(0);
        if (i + 2 < nsteps) STAGE(i + 2);          // rides the next step
    }
#undef STAGE
#undef COMPUTE

    // ---- store partials
    const int hcol = ht * 32 + l31;                // global h (actor|critic)
    float* Pb = P + (size_t)s * T_STEPS * HTOT;
#pragma unroll
    for (int reg = 0; reg < 16; reg++) {
        const int t = wt + (reg & 3) + 4 * h5 + 8 * (reg >> 2);
        if (t < T_STEPS) Pb[(size_t)t * HTOT + hcol] = acc[reg];
    }
}

// ---- fused reduce + LIF1: 8 blocks x 512 thr; block owns 64 neurons.
// Phase 1: reduce P over splits into LDS; phase 2: wave 0 runs LIF + ballot.
__global__ __launch_bounds__(512) void k_rlif(
    const float* __restrict__ P,               // [NS][100][512]
    const float* __restrict__ ab1, const float* __restrict__ cb1,
    unsigned long long* __restrict__ bitsws,   // [100][8]
    float* __restrict__ wsa, int NS)
{
    const int b   = blockIdx.x;    // 0..7
    const int n0  = b * 64;
    const int tid = threadIdx.x;

    __shared__ float cur1L[T_STEPS][64];

    for (int idx = tid; idx < T_STEPS * 64; idx += 512) {
        const int c = idx & 63, t = idx >> 6;
        const int h = n0 + c;
        float sum = (h < HID) ? ab1[h] : cb1[h - HID];
        for (int ss = 0; ss < NS; ss++)
            sum += P[(size_t)ss * T_STEPS * HTOT + (size_t)t * HTOT + h];
        cur1L[t][c] = sum;
    }
    __syncthreads();

    if (tid < 64) {
        float mem = 0.f;
        for (int t = 0; t < T_STEPS; t++) {
            float reset = (mem > THRESH) ? THRESH : 0.f;
            mem = BETA * mem + cur1L[t][tid] - reset;
            unsigned long long m = __ballot(mem > THRESH);
            if (tid == 0) bitsws[(size_t)t * 8 + b] = m;
        }
    }
    if (b == 0 && tid == 0) { wsa[0] = 0.f; wsa[1] = 0.f; }
}

// GEMM2 + LIF2: block per output neuron j (0..19 actor, 20 critic).
__global__ __launch_bounds__(128) void k_gemm2(
    const unsigned long long* __restrict__ bitsws,
    const float* __restrict__ aW2, const float* __restrict__ ab2,
    const float* __restrict__ cW2, const float* __restrict__ cb2,
    float* __restrict__ wsa, float* __restrict__ out)
{
    const int j   = blockIdx.x;
    const int tid = threadIdx.x;

    __shared__ float W[256];
    __shared__ float c2[T_STEPS];

    const float* Wsrc = (j < 20) ? (aW2 + j * 256) : cW2;
    for (int i = tid; i < 256; i += 128) W[i] = Wsrc[i];
    const float bias  = (j < 20) ? ab2[j] : cb2[0];
    const int   wbase = (j < 20) ? 0 : 4;
    __syncthreads();

    const int t = tid;
    if (t < T_STEPS) {
        unsigned long long m0 = bitsws[(size_t)t * 8 + wbase + 0];
        unsigned long long m1 = bitsws[(size_t)t * 8 + wbase + 1];
        unsigned long long m2 = bitsws[(size_t)t * 8 + wbase + 2];
        unsigned long long m3 = bitsws[(size_t)t * 8 + wbase + 3];
        float acc = bias;
#pragma unroll
        for (int bitp = 0; bitp < 64; bitp++) {
            acc += ((m0 >> bitp) & 1ULL) ? W[bitp]       : 0.f;
            acc += ((m1 >> bitp) & 1ULL) ? W[64 + bitp]  : 0.f;
            acc += ((m2 >> bitp) & 1ULL) ? W[128 + bitp] : 0.f;
            acc += ((m3 >> bitp) & 1ULL) ? W[192 + bitp] : 0.f;
        }
        c2[t] = acc;
    }
    __syncthreads();

    if (tid == 0) {
        float mem = 0.f, spk = 0.f;
        for (int tt = 0; tt < T_STEPS; tt++) {
            float reset = (mem > THRESH) ? THRESH : 0.f;
            mem = BETA * mem + c2[tt] - reset;
            spk += (mem > THRESH) ? 1.f : 0.f;
        }
        if (j < 10)       atomicAdd(&wsa[0], spk);   // exact: integer-valued floats
        else if (j < 20)  atomicAdd(&wsa[1], spk);
        else              out[2] = mem;
    }
}

__global__ __launch_bounds__(64) void k_final(
    const float* __restrict__ wsa, float* __restrict__ out)
{
    if (threadIdx.x == 0) {
        float a0 = wsa[0], a1 = wsa[1];
        float mx = fmaxf(a0, a1);
        float e0 = expf(a0 - mx), e1 = expf(a1 - mx);
        float inv = 1.f / (e0 + e1);
        out[0] = e0 * inv;
        out[1] = e1 * inv;
    }
}

extern "C" void kernel_launch(void* const* d_in, const int* in_sizes, int n_in,
                              void* d_out, int out_size, void* d_ws, size_t ws_size,
                              hipStream_t stream) {
    const float* x   = (const float*)d_in[0];
    const float* aW1 = (const float*)d_in[1];
    const float* ab1 = (const float*)d_in[2];
    const float* aW2 = (const float*)d_in[3];
    const float* ab2 = (const float*)d_in[4];
    const float* cW1 = (const float*)d_in[5];
    const float* cb1 = (const float*)d_in[6];
    const float* cW2 = (const float*)d_in[7];
    const float* cb2 = (const float*)d_in[8];
    float* out = (float*)d_out;

    const size_t xpack_bytes = 2048ull * 16384;            // 33.55 MB
    int NS = 64;
    while (NS > 8 &&
           xpack_bytes + ((size_t)NS * T_STEPS * HTOT) * sizeof(float)
               + 8192 > ws_size)
        NS >>= 1;
    const int nsteps = (D_IN / NS) / 32;   // 32-k steps per split

    __bf16* xpack = (__bf16*)d_ws;
    float*  P     = (float*)((char*)d_ws + xpack_bytes);   // [NS][100][512]
    unsigned long long* bitsws =
        (unsigned long long*)(P + (size_t)NS * T_STEPS * HTOT);  // [100][8]
    float* wsa = (float*)(bitsws + T_STEPS * 8);           // [2]

    k_xpack <<<2048, 512, 0, stream>>>(x, xpack);
    k_gemm1 <<<dim3(16, NS), 256, 0, stream>>>(aW1, cW1, xpack, P, nsteps);
    k_rlif  <<<8, 512, 0, stream>>>(P, ab1, cb1, bitsws, wsa, NS);
    k_gemm2 <<<21, 128, 0, stream>>>(bitsws, aW2, ab2, cW2, cb2, wsa, out);
    k_final <<<1, 64, 0, stream>>>(wsa, out);
}

// Round 11
// 96.288 us; speedup vs baseline: 3.0515x; 3.0515x over previous
//
#include <hip/hip_runtime.h>
#include <hip/hip_bf16.h>

#define T_STEPS 100
#define D_IN    65536
#define HID     256
#define HTOT    512
#define BETA    0.95f
#define THRESH  1.0f

typedef __bf16 bf16x8 __attribute__((ext_vector_type(8)));
typedef float  f32x16 __attribute__((ext_vector_type(16)));

__device__ __forceinline__ void gload_lds16(const void* g, void* l) {
    __builtin_amdgcn_global_load_lds(
        (const __attribute__((address_space(1))) void*)g,
        (__attribute__((address_space(3))) void*)l, 16, 0, 0);
}

// ---- x pre-pack: fp32 -> bf16 hi/mid blobs, one 16-KB blob per 32-k block.
// Blob layout == gemm1 LDS x-layout: granule G(r,slot) = r*4 + (slot^((r>>1)&3)),
// hi at G*16 bytes, mid at 8 KB + G*16. Rows 100..127 zero-padded.
__global__ __launch_bounds__(512) void k_xpack(
    const float* __restrict__ x, __bf16* __restrict__ xp)
{
    const int idx  = blockIdx.x * 512 + threadIdx.x;
    const int slot = idx & 3;
    const int r    = (idx >> 2) & 127;
    const int gk   = idx >> 9;

    float f[8] = {0.f, 0.f, 0.f, 0.f, 0.f, 0.f, 0.f, 0.f};
    if (r < T_STEPS) {
        const float* src = x + (size_t)r * D_IN + gk * 32 + slot * 8;
        float4 v0 = *(const float4*)src;
        float4 v1 = *(const float4*)(src + 4);
        f[0] = v0.x; f[1] = v0.y; f[2] = v0.z; f[3] = v0.w;
        f[4] = v1.x; f[5] = v1.y; f[6] = v1.z; f[7] = v1.w;
    }
    bf16x8 hi, mi;
#pragma unroll
    for (int e = 0; e < 8; e++) {
        __bf16 h = (__bf16)f[e];
        hi[e] = h; mi[e] = (__bf16)(f[e] - (float)h);
    }
    const int G = r * 4 + (slot ^ ((r >> 1) & 3));
    __bf16* blob = xp + (size_t)gk * 8192;
    *(bf16x8*)(blob + G * 8)        = hi;
    *(bf16x8*)(blob + 4096 + G * 8) = mi;
}

// ---- GEMM1 (R8 structure + XCD-locality block swizzle).
// 2-buffer gload_lds pipeline, 64 KB LDS -> 2 blocks/CU. Per 32-k step-buffer
// (32 KB): [0,8K) x_h, [8K,16K) x_m, [16K,32K) W fp32 (row-swizzled source).
// 3-product bf16 hi/mid MFMA. Flat grid 512: d -> (ht, s) such that all 4
// h-tiles of a split (and 16 adjacent splits) land on the SAME XCD -> the
// split's x blobs are fetched into that XCD's L2 once, not 4x via L3.
// block 512 = 8 waves (2t x 4h, each 64t x 32h).
__global__ __launch_bounds__(512, 4) void k_gemm1(
    const float* __restrict__ aW1,   // [256][65536]
    const float* __restrict__ cW1,   // [256][65536]
    const __bf16* __restrict__ xp,   // packed x blobs
    float* __restrict__ P,           // [NS][100][512]
    int nsteps)                      // 32-k steps per split (16 at NS=128)
{
    // bijective swizzle: d in [0,512) -> xcd = d%8, slot = d/8 (0..63),
    // s = xcd*16 + (slot & 15)  (0..127), ht = slot >> 4 (0..3)
    const int d    = blockIdx.x;
    const int xcd  = d & 7;
    const int slot = d >> 3;
    const int s    = xcd * 16 + (slot & 15);
    const int ht   = slot >> 4;

    const int tid  = threadIdx.x;
    const int lane = tid & 63;
    const int l31  = lane & 31;
    const int wv   = tid >> 6;           // 0..7
    const int wt   = (wv & 1) * 64;
    const int hq   = (wv >> 1) * 32;

    __shared__ __align__(16) char smem[2][32768];   // 64 KB

    const float* Wbase = (ht < 2) ? (aW1 + (size_t)ht * 128 * D_IN)
                                  : (cW1 + (size_t)(ht - 2) * 128 * D_IN);

    // 4 global_load_lds per thread per step
    const int gx0 = wv * 64 + lane;      // x granule op0 (0..511)
    const int gx1 = 512 + gx0;           // x granule op1 (512..1023)
    const int wr0 = gx0 >> 3, wj0 = gx0 & 7;   // W granule op2
    const int wr1 = gx1 >> 3, wj1 = gx1 & 7;   // W granule op3
    const float* wsrc0 = Wbase + (size_t)wr0 * D_IN + (wj0 ^ (wr0 & 7)) * 4;
    const float* wsrc1 = Wbase + (size_t)wr1 * D_IN + (wj1 ^ (wr1 & 7)) * 4;
    const int gk0 = s * nsteps;

    f32x16 acc0, acc1;
#pragma unroll
    for (int i = 0; i < 16; i++) { acc0[i] = 0.f; acc1[i] = 0.f; }

#define STAGE(i) do {                                                         \
    char* b_ = smem[(i) & 1];                                                 \
    const __bf16* xb_ = xp + (size_t)(gk0 + (i)) * 8192;                      \
    const int kc_ = (gk0 + (i)) * 32;                                         \
    gload_lds16(xb_ + gx0 * 8, b_ + gx0 * 16);                                \
    gload_lds16(xb_ + gx1 * 8, b_ + gx1 * 16);                                \
    gload_lds16(wsrc0 + kc_, b_ + 16384 + gx0 * 16);                          \
    gload_lds16(wsrc1 + kc_, b_ + 16384 + gx1 * 16);                          \
} while (0)

#define COMPUTE(i) do {                                                       \
    const char* b_ = smem[(i) & 1];                                           \
    _Pragma("unroll")                                                         \
    for (int s16 = 0; s16 < 2; s16++) {                                       \
        const int hr = hq + l31;                                              \
        const int gb = s16 * 4 + (lane >> 5) * 2;                             \
        const char* wrow_ = b_ + 16384 + hr * 128;                            \
        float4 wa = *(const float4*)(wrow_ + ((gb ^ (hr & 7)) * 16));         \
        float4 wb = *(const float4*)(wrow_ + (((gb + 1) ^ (hr & 7)) * 16));   \
        float fb[8] = {wa.x, wa.y, wa.z, wa.w, wb.x, wb.y, wb.z, wb.w};       \
        bf16x8 bh, bm;                                                        \
        _Pragma("unroll")                                                     \
        for (int e = 0; e < 8; e++) {                                         \
            __bf16 h = (__bf16)fb[e];                                         \
            bh[e] = h; bm[e] = (__bf16)(fb[e] - (float)h);                    \
        }                                                                     \
        const int slot_ = s16 * 2 + (lane >> 5);                              \
        const int r0 = wt + l31, r1 = r0 + 32;                                \
        const int G0 = r0 * 4 + (slot_ ^ ((r0 >> 1) & 3));                    \
        const int G1 = r1 * 4 + (slot_ ^ ((r1 >> 1) & 3));                    \
        bf16x8 a0h = *(const bf16x8*)(b_ + G0 * 16);                          \
        bf16x8 a0m = *(const bf16x8*)(b_ + 8192 + G0 * 16);                   \
        bf16x8 a1h = *(const bf16x8*)(b_ + G1 * 16);                          \
        bf16x8 a1m = *(const bf16x8*)(b_ + 8192 + G1 * 16);                   \
        acc0 = __builtin_amdgcn_mfma_f32_32x32x16_bf16(a0m, bh, acc0, 0,0,0); \
        acc0 = __builtin_amdgcn_mfma_f32_32x32x16_bf16(a0h, bm, acc0, 0,0,0); \
        acc0 = __builtin_amdgcn_mfma_f32_32x32x16_bf16(a0h, bh, acc0, 0,0,0); \
        acc1 = __builtin_amdgcn_mfma_f32_32x32x16_bf16(a1m, bh, acc1, 0,0,0); \
        acc1 = __builtin_amdgcn_mfma_f32_32x32x16_bf16(a1h, bm, acc1, 0,0,0); \
        acc1 = __builtin_amdgcn_mfma_f32_32x32x16_bf16(a1h, bh, acc1, 0,0,0); \
    }                                                                         \
} while (0)

    STAGE(0);
    STAGE(1);
    for (int i = 0; i < nsteps; i++) {
        if (i + 1 < nsteps) asm volatile("s_waitcnt vmcnt(4)" ::: "memory");
        else                asm volatile("s_waitcnt vmcnt(0)" ::: "memory");
        __builtin_amdgcn_s_barrier();              // buf[i&1] staged for all
        __builtin_amdgcn_sched_barrier(0);
        COMPUTE(i);
        __builtin_amdgcn_s_barrier();              // all waves done with buf
        __builtin_amdgcn_sched_barrier(0);
        if (i + 2 < nsteps) STAGE(i + 2);          // rides the next step
    }
#undef STAGE
#undef COMPUTE

    // ---- store partials
    const int rbase = 4 * (lane >> 5);
    const int hcol  = ht * 128 + hq + l31;
    float* Pb = P + (size_t)s * T_STEPS * HTOT;
#pragma unroll
    for (int reg = 0; reg < 16; reg++) {
        const int row = (reg & 3) + rbase + 8 * (reg >> 2);
        const int t0  = wt + row;
        const int t1  = wt + 32 + row;
        if (t0 < T_STEPS) Pb[(size_t)t0 * HTOT + hcol] = acc0[reg];
        if (t1 < T_STEPS) Pb[(size_t)t1 * HTOT + hcol] = acc1[reg];
    }
}

// reduce partials + bias -> cur1[t][h]   (float4 per thread, coalesced)
__global__ __launch_bounds__(256) void k_reduce(
    const float* __restrict__ P,
    const float* __restrict__ ab1, const float* __restrict__ cb1,
    float* __restrict__ cur1, int NS)
{
    int g4 = blockIdx.x * 256 + threadIdx.x;
    int g  = g4 * 4;
    int h0 = g & (HTOT - 1);
    float4 sum;
    sum.x = (h0 + 0 < HID) ? ab1[h0 + 0] : cb1[h0 + 0 - HID];
    sum.y = (h0 + 1 < HID) ? ab1[h0 + 1] : cb1[h0 + 1 - HID];
    sum.z = (h0 + 2 < HID) ? ab1[h0 + 2] : cb1[h0 + 2 - HID];
    sum.w = (h0 + 3 < HID) ? ab1[h0 + 3] : cb1[h0 + 3 - HID];
    for (int ss = 0; ss < NS; ss++) {
        float4 v = *(const float4*)(P + (size_t)ss * T_STEPS * HTOT + g);
        sum.x += v.x; sum.y += v.y; sum.z += v.z; sum.w += v.w;
    }
    *(float4*)(cur1 + g) = sum;
}

// LIF1: 8 blocks x 64 threads, thread = neuron, 10-deep current prefetch.
__global__ __launch_bounds__(64) void k_lif1(
    const float* __restrict__ cur1,
    unsigned long long* __restrict__ bitsws,
    float* __restrict__ wsa)
{
    const int b    = blockIdx.x;
    const int lane = threadIdx.x;
    const int n    = b * 64 + lane;

    float mem = 0.f;
    for (int tb = 0; tb < T_STEPS; tb += 10) {
        float c[10];
#pragma unroll
        for (int i = 0; i < 10; i++) c[i] = cur1[(size_t)(tb + i) * HTOT + n];
#pragma unroll
        for (int i = 0; i < 10; i++) {
            float reset = (mem > THRESH) ? THRESH : 0.f;
            mem = BETA * mem + c[i] - reset;
            unsigned long long m = __ballot(mem > THRESH);
            if (lane == 0) bitsws[(size_t)(tb + i) * 8 + b] = m;
        }
    }
    if (b == 0 && lane == 0) { wsa[0] = 0.f; wsa[1] = 0.f; }
}

// GEMM2 + LIF2: block per output neuron j (0..19 actor, 20 critic).
__global__ __launch_bounds__(128) void k_gemm2(
    const unsigned long long* __restrict__ bitsws,
    const float* __restrict__ aW2, const float* __restrict__ ab2,
    const float* __restrict__ cW2, const float* __restrict__ cb2,
    float* __restrict__ wsa, float* __restrict__ out)
{
    const int j   = blockIdx.x;
    const int tid = threadIdx.x;

    __shared__ float W[256];
    __shared__ float c2[T_STEPS];

    const float* Wsrc = (j < 20) ? (aW2 + j * 256) : cW2;
    for (int i = tid; i < 256; i += 128) W[i] = Wsrc[i];
    const float bias  = (j < 20) ? ab2[j] : cb2[0];
    const int   wbase = (j < 20) ? 0 : 4;
    __syncthreads();

    const int t = tid;
    if (t < T_STEPS) {
        unsigned long long m0 = bitsws[(size_t)t * 8 + wbase + 0];
        unsigned long long m1 = bitsws[(size_t)t * 8 + wbase + 1];
        unsigned long long m2 = bitsws[(size_t)t * 8 + wbase + 2];
        unsigned long long m3 = bitsws[(size_t)t * 8 + wbase + 3];
        float acc = bias;
#pragma unroll
        for (int bitp = 0; bitp < 64; bitp++) {
            acc += ((m0 >> bitp) & 1ULL) ? W[bitp]       : 0.f;
            acc += ((m1 >> bitp) & 1ULL) ? W[64 + bitp]  : 0.f;
            acc += ((m2 >> bitp) & 1ULL) ? W[128 + bitp] : 0.f;
            acc += ((m3 >> bitp) & 1ULL) ? W[192 + bitp] : 0.f;
        }
        c2[t] = acc;
    }
    __syncthreads();

    if (tid == 0) {
        float mem = 0.f, spk = 0.f;
        for (int tt = 0; tt < T_STEPS; tt++) {
            float reset = (mem > THRESH) ? THRESH : 0.f;
            mem = BETA * mem + c2[tt] - reset;
            spk += (mem > THRESH) ? 1.f : 0.f;
        }
        if (j < 10)       atomicAdd(&wsa[0], spk);   // exact: integer-valued floats
        else if (j < 20)  atomicAdd(&wsa[1], spk);
        else              out[2] = mem;
    }
}

__global__ __launch_bounds__(64) void k_final(
    const float* __restrict__ wsa, float* __restrict__ out)
{
    if (threadIdx.x == 0) {
        float a0 = wsa[0], a1 = wsa[1];
        float mx = fmaxf(a0, a1);
        float e0 = expf(a0 - mx), e1 = expf(a1 - mx);
        float inv = 1.f / (e0 + e1);
        out[0] = e0 * inv;
        out[1] = e1 * inv;
    }
}

extern "C" void kernel_launch(void* const* d_in, const int* in_sizes, int n_in,
                              void* d_out, int out_size, void* d_ws, size_t ws_size,
                              hipStream_t stream) {
    const float* x   = (const float*)d_in[0];
    const float* aW1 = (const float*)d_in[1];
    const float* ab1 = (const float*)d_in[2];
    const float* aW2 = (const float*)d_in[3];
    const float* ab2 = (const float*)d_in[4];
    const float* cW1 = (const float*)d_in[5];
    const float* cb1 = (const float*)d_in[6];
    const float* cW2 = (const float*)d_in[7];
    const float* cb2 = (const float*)d_in[8];
    float* out = (float*)d_out;

    const size_t xpack_bytes = 2048ull * 16384;            // 33.55 MB
    const int NS = 128;                                    // fixed (swizzle assumes 128)
    const int nsteps = (D_IN / NS) / 32;                   // 16

    __bf16* xpack = (__bf16*)d_ws;
    float*  P     = (float*)((char*)d_ws + xpack_bytes);   // [128][100][512]
    float*  cur1  = P + (size_t)NS * T_STEPS * HTOT;       // [100][512]
    unsigned long long* bitsws =
        (unsigned long long*)(cur1 + T_STEPS * HTOT);      // [100][8]
    float* wsa = (float*)(bitsws + T_STEPS * 8);           // [2]

    k_xpack <<<2048, 512, 0, stream>>>(x, xpack);
    k_gemm1 <<<512, 512, 0, stream>>>(aW1, cW1, xpack, P, nsteps);
    k_reduce<<<(T_STEPS * HTOT / 4) / 256, 256, 0, stream>>>(P, ab1, cb1, cur1, NS);
    k_lif1  <<<8, 64, 0, stream>>>(cur1, bitsws, wsa);
    k_gemm2 <<<21, 128, 0, stream>>>(bitsws, aW2, ab2, cW2, cb2, wsa, out);
    k_final <<<1, 64, 0, stream>>>(wsa, out);
}